// Round 2
// baseline (530.882 us; speedup 1.0000x reference)
//
#include <hip/hip_runtime.h>
#include <hip/hip_bf16.h>
#include <stdint.h>

typedef __attribute__((ext_vector_type(8))) short short8;
typedef __attribute__((ext_vector_type(4))) float floatx4;

// ---- problem constants ----
// x: [8, 64, 256, 256] fp32; windows 32x32, patches 4x4 -> 512 windows x 64 tokens x 1024 dims
constexpr int TD    = 1024;   // token dim
constexpr int E3    = 1536;   // 3*inner
constexpr int INNER = 512;
constexpr int NW    = 512;    // windows
constexpr int M_    = NW * 64; // 32768 tokens

// K-order permutation: reference d = p1*256 + p2*64 + c  <->  d' = c*16 + p1*4 + p2

// ---- workspace layout (bytes) ----
constexpr size_t OFF_TOKA = 0;                                 // tokens bf16 [M, 1024] (64 MB); oattn aliases here later
constexpr size_t OFF_QKV  = (size_t)M_ * TD * 2;               // qkv bf16 [M, 1536] (96 MB)
constexpr size_t OFF_WQT  = OFF_QKV + (size_t)M_ * E3 * 2;     // w_qkv^T bf16 [1536, 1024] (3 MB)
constexpr size_t OFF_WOT  = OFF_WQT + (size_t)E3 * TD * 2;     // w_out^T bf16 [1024, 512] (1 MB)
constexpr size_t OFF_BO   = OFF_WOT + (size_t)TD * INNER * 2;  // bias' fp32 [1024]
constexpr size_t WS_NEED  = OFF_BO + TD * 4;

__device__ __forceinline__ void gl_lds16(const void* g, void* l) {
  __builtin_amdgcn_global_load_lds(
      (const __attribute__((address_space(1))) void*)g,
      (__attribute__((address_space(3))) void*)l, 16, 0, 0);
}

// ---- patchify: x [8,64,256,256] -> tokens bf16 [M, 1024] in d' order ----
__global__ __launch_bounds__(256) void k_patchify(const float* __restrict__ x,
                                                  __hip_bfloat16* __restrict__ tokA) {
  __shared__ __hip_bfloat16 tok[8][1032];  // 8 tokens (one i-row) x 1024 d', padded
  const int bid = blockIdx.x;
  const int n = bid >> 3, i = bid & 7;               // window, token-row
  const int b = n >> 6, h1 = (n >> 3) & 7, w1 = n & 7;
  const int tid = threadIdx.x;
  // load 64c x 4p1 x 32w floats, coalesced float4 (one float4 = one (j), p2=0..3)
  for (int it = 0; it < 8; ++it) {
    int idx = it * 256 + tid;            // [0, 2048)
    int w4 = idx & 7, p1 = (idx >> 3) & 3, c = idx >> 5;
    int h = h1 * 32 + i * 4 + p1;
    const float4 v = *(const float4*)&x[(((b * 64 + c) * 256 + h) * 256 + w1 * 32 + w4 * 4)];
    __hip_bfloat16* dst = &tok[w4][c * 16 + p1 * 4];
    dst[0] = __float2bfloat16(v.x);
    dst[1] = __float2bfloat16(v.y);
    dst[2] = __float2bfloat16(v.z);
    dst[3] = __float2bfloat16(v.w);
  }
  __syncthreads();
  // write 8 token rows of 1024 bf16, coalesced 16B
  for (int it = 0; it < 4; ++it) {
    int idx = it * 256 + tid;            // [0, 1024)
    int ch = idx & 127, j = idx >> 7;
    uint4 v = *(const uint4*)&tok[j][ch * 8];
    *(uint4*)&tokA[(size_t)(n * 64 + i * 8 + j) * 1024 + ch * 8] = v;
  }
}

// ---- w_qkv [1024 d][1536 e] fp32 -> wqT bf16 [1536 e][1024 d'] ----
__global__ __launch_bounds__(256) void k_perm_wqkv(const float* __restrict__ wqkv,
                                                   __hip_bfloat16* __restrict__ wqT) {
  __shared__ __hip_bfloat16 wt[16][1032];
  const int e0 = blockIdx.x * 16, tid = threadIdx.x;
  for (int it = 0; it < 64; ++it) {
    int idx = it * 256 + tid;            // d*16 + e
    int e = idx & 15, d = idx >> 4;
    float v = wqkv[d * 1536 + e0 + e];
    int p1 = d >> 8, p2 = (d >> 6) & 3, c = d & 63;
    wt[e][c * 16 + p1 * 4 + p2] = __float2bfloat16(v);
  }
  __syncthreads();
  for (int it = 0; it < 8; ++it) {
    int idx = it * 256 + tid;            // [0, 2048)
    int ch = idx & 127, e = idx >> 7;
    uint4 v = *(const uint4*)&wt[e][ch * 8];
    *(uint4*)&wqT[(size_t)(e0 + e) * 1024 + ch * 8] = v;
  }
}

// ---- w_out [512 e][1024 d] fp32 -> woT bf16 [1024 d'][512 e] ----
__global__ __launch_bounds__(256) void k_perm_wout(const float* __restrict__ wout,
                                                   __hip_bfloat16* __restrict__ woT) {
  __shared__ __hip_bfloat16 wt[16][1032];
  const int e0 = blockIdx.x * 16, tid = threadIdx.x;
  for (int it = 0; it < 64; ++it) {
    int idx = it * 256 + tid;            // e*1024 + d
    int d = idx & 1023, e = idx >> 10;
    float v = wout[(e0 + e) * 1024 + d];
    int p1 = d >> 8, p2 = (d >> 6) & 3, c = d & 63;
    wt[e][c * 16 + p1 * 4 + p2] = __float2bfloat16(v);
  }
  __syncthreads();
  for (int it = 0; it < 64; ++it) {
    int idx = it * 256 + tid;            // dp*16 + e
    int e = idx & 15, dp = idx >> 4;
    woT[(size_t)dp * 512 + e0 + e] = wt[e][dp];
  }
}

__global__ __launch_bounds__(256) void k_perm_bias(const float* __restrict__ bout,
                                                   float* __restrict__ boP) {
  int dp = blockIdx.x * 256 + threadIdx.x;
  int c = dp >> 4, p1 = (dp >> 2) & 3, p2 = dp & 3;
  boP[dp] = bout[p1 * 256 + p2 * 64 + c];
}

// ---- GEMM1: tokens [M,1024] x wqT^T -> qkv bf16 [M,1536] (m97 structure) ----
__global__ __launch_bounds__(256) void k_gemm_qkv(const __hip_bfloat16* __restrict__ A,
                                                  const __hip_bfloat16* __restrict__ Bt,
                                                  __hip_bfloat16* __restrict__ Cmat) {
  constexpr int K = 1024, N = 1536;
  __shared__ __hip_bfloat16 As[128 * 64];
  __shared__ __hip_bfloat16 Bs[128 * 64];
  const int tid = threadIdx.x;
  const int m0 = blockIdx.x * 128, n0 = blockIdx.y * 128;
  const int lane = tid & 63, wid = tid >> 6;
  const int wm = wid & 1, wn = wid >> 1;
  const int l15 = lane & 15, quad = lane >> 4, q8 = quad * 8;
  floatx4 acc[4][4] = {};
  for (int k0 = 0; k0 < K; k0 += 64) {
    __syncthreads();
    for (int it = 0; it < 4; ++it) {
      int ci = it * 256 + tid;
      int r = ci >> 3, ch = ci & 7;
      gl_lds16(&A[(size_t)(m0 + r) * K + k0 + ch * 8], (char*)As + ci * 16);
      gl_lds16(&Bt[(size_t)(n0 + r) * K + k0 + ch * 8], (char*)Bs + ci * 16);
    }
    __syncthreads();
#pragma unroll
    for (int kk = 0; kk < 64; kk += 32) {
      short8 af[4], bf[4];
#pragma unroll
      for (int mt = 0; mt < 4; ++mt)
        af[mt] = *(const short8*)&As[(wm * 64 + mt * 16 + l15) * 64 + kk + q8];
#pragma unroll
      for (int nt = 0; nt < 4; ++nt)
        bf[nt] = *(const short8*)&Bs[(wn * 64 + nt * 16 + l15) * 64 + kk + q8];
#pragma unroll
      for (int mt = 0; mt < 4; ++mt)
#pragma unroll
        for (int nt = 0; nt < 4; ++nt)
          acc[mt][nt] = __builtin_amdgcn_mfma_f32_16x16x32_bf16(af[mt], bf[nt], acc[mt][nt], 0, 0, 0);
    }
  }
#pragma unroll
  for (int mt = 0; mt < 4; ++mt)
#pragma unroll
    for (int nt = 0; nt < 4; ++nt) {
      int col = n0 + wn * 64 + nt * 16 + l15;
#pragma unroll
      for (int r = 0; r < 4; ++r) {
        int row = m0 + wm * 64 + mt * 16 + quad * 4 + r;
        Cmat[(size_t)row * N + col] = __float2bfloat16(acc[mt][nt][r]);
      }
    }
}

// ---- attention: one block per (window, head) ----
__global__ __launch_bounds__(256) void k_attn(const __hip_bfloat16* __restrict__ qkv,
                                              __hip_bfloat16* __restrict__ oattn) {
  __shared__ __hip_bfloat16 Qs[64 * 64];   // [t][dh]
  __shared__ __hip_bfloat16 Ks[64 * 64];   // [t][dh]
  __shared__ __hip_bfloat16 Vt[64 * 72];   // [dh][t] padded
  __shared__ __hip_bfloat16 Ps[64 * 72];   // [t][t'] padded
  const int win = blockIdx.x, head = blockIdx.y;
  const int tid = threadIdx.x, lane = tid & 63, wid = tid >> 6;
  const int l15 = lane & 15, quad = lane >> 4, q8 = quad * 8;
  const size_t base = (size_t)win * 64 * 1536 + head * 64;
  for (int l = 0; l < 2; ++l) {
    int idx = l * 256 + tid;             // t*8 + ch
    int t = idx >> 3, ch = idx & 7;
    const size_t rowb = base + (size_t)t * 1536 + ch * 8;
    uint4 q = *(const uint4*)&qkv[rowb];
    uint4 k = *(const uint4*)&qkv[rowb + 512];
    uint4 v = *(const uint4*)&qkv[rowb + 1024];
    *(uint4*)&Qs[t * 64 + ch * 8] = q;
    *(uint4*)&Ks[t * 64 + ch * 8] = k;
    const __hip_bfloat16* pv = (const __hip_bfloat16*)&v;
#pragma unroll
    for (int jj = 0; jj < 8; ++jj) Vt[(ch * 8 + jj) * 72 + t] = pv[jj];
  }
  __syncthreads();
  // S = Q K^T * scale ; wave computes 16-row strip
  floatx4 sacc[4] = {};
#pragma unroll
  for (int kk = 0; kk < 64; kk += 32) {
    short8 aq = *(const short8*)&Qs[(wid * 16 + l15) * 64 + kk + q8];
#pragma unroll
    for (int ct = 0; ct < 4; ++ct) {
      short8 bk = *(const short8*)&Ks[(ct * 16 + l15) * 64 + kk + q8];
      sacc[ct] = __builtin_amdgcn_mfma_f32_16x16x32_bf16(aq, bk, sacc[ct], 0, 0, 0);
    }
  }
#pragma unroll
  for (int ct = 0; ct < 4; ++ct)
#pragma unroll
    for (int r = 0; r < 4; ++r) sacc[ct][r] = sacc[ct][r] * 0.125f;
  // softmax per row (row = wid*16 + quad*4 + r, cols spread over 16 lanes x 4 ct)
#pragma unroll
  for (int r = 0; r < 4; ++r) {
    float m = fmaxf(fmaxf(sacc[0][r], sacc[1][r]), fmaxf(sacc[2][r], sacc[3][r]));
    m = fmaxf(m, __shfl_xor(m, 1));
    m = fmaxf(m, __shfl_xor(m, 2));
    m = fmaxf(m, __shfl_xor(m, 4));
    m = fmaxf(m, __shfl_xor(m, 8));
    float ev[4]; float s0 = 0.f;
#pragma unroll
    for (int ct = 0; ct < 4; ++ct) { ev[ct] = __expf(sacc[ct][r] - m); s0 += ev[ct]; }
    s0 += __shfl_xor(s0, 1);
    s0 += __shfl_xor(s0, 2);
    s0 += __shfl_xor(s0, 4);
    s0 += __shfl_xor(s0, 8);
    float inv = 1.0f / s0;
    int row = wid * 16 + quad * 4 + r;
#pragma unroll
    for (int ct = 0; ct < 4; ++ct)
      Ps[row * 72 + ct * 16 + l15] = __float2bfloat16(ev[ct] * inv);
  }
  __syncthreads();
  // O = P V
  floatx4 oacc[4] = {};
#pragma unroll
  for (int kk = 0; kk < 64; kk += 32) {
    short8 ap = *(const short8*)&Ps[(wid * 16 + l15) * 72 + kk + q8];
#pragma unroll
    for (int nt = 0; nt < 4; ++nt) {
      short8 bv = *(const short8*)&Vt[(nt * 16 + l15) * 72 + kk + q8];
      oacc[nt] = __builtin_amdgcn_mfma_f32_16x16x32_bf16(ap, bv, oacc[nt], 0, 0, 0);
    }
  }
#pragma unroll
  for (int nt = 0; nt < 4; ++nt) {
    int dh = nt * 16 + l15;
#pragma unroll
    for (int r = 0; r < 4; ++r) {
      int t = wid * 16 + quad * 4 + r;
      oattn[((size_t)win * 64 + t) * 512 + head * 64 + dh] = __float2bfloat16(oacc[nt][r]);
    }
  }
}

// ---- GEMM2 + bias + un-patchify scatter: oattn [M,512] x woT^T -> out [8,64,256,256] ----
__global__ __launch_bounds__(256) void k_gemm_out(const __hip_bfloat16* __restrict__ A,
                                                  const __hip_bfloat16* __restrict__ Bt,
                                                  const float* __restrict__ bias,
                                                  float* __restrict__ out) {
  constexpr int K = 512;
  __shared__ __hip_bfloat16 As[128 * 64];
  __shared__ __hip_bfloat16 Bs[128 * 64];
  const int tid = threadIdx.x;
  const int m0 = blockIdx.x * 128, n0 = blockIdx.y * 128;
  const int lane = tid & 63, wid = tid >> 6;
  const int wm = wid & 1, wn = wid >> 1;
  const int l15 = lane & 15, quad = lane >> 4, q8 = quad * 8;
  floatx4 acc[4][4] = {};
  for (int k0 = 0; k0 < K; k0 += 64) {
    __syncthreads();
    for (int it = 0; it < 4; ++it) {
      int ci = it * 256 + tid;
      int r = ci >> 3, ch = ci & 7;
      gl_lds16(&A[(size_t)(m0 + r) * K + k0 + ch * 8], (char*)As + ci * 16);
      gl_lds16(&Bt[(size_t)(n0 + r) * K + k0 + ch * 8], (char*)Bs + ci * 16);
    }
    __syncthreads();
#pragma unroll
    for (int kk = 0; kk < 64; kk += 32) {
      short8 af[4], bf[4];
#pragma unroll
      for (int mt = 0; mt < 4; ++mt)
        af[mt] = *(const short8*)&As[(wm * 64 + mt * 16 + l15) * 64 + kk + q8];
#pragma unroll
      for (int nt = 0; nt < 4; ++nt)
        bf[nt] = *(const short8*)&Bs[(wn * 64 + nt * 16 + l15) * 64 + kk + q8];
#pragma unroll
      for (int mt = 0; mt < 4; ++mt)
#pragma unroll
        for (int nt = 0; nt < 4; ++nt)
          acc[mt][nt] = __builtin_amdgcn_mfma_f32_16x16x32_bf16(af[mt], bf[nt], acc[mt][nt], 0, 0, 0);
    }
  }
  // epilogue: bias + scatter to [b, c, h, w]
#pragma unroll
  for (int nt = 0; nt < 4; ++nt) {
    int dp = n0 + wn * 64 + nt * 16 + l15;        // d'
    float bv = bias[dp];
    int c = dp >> 4, p1 = (dp >> 2) & 3, p2 = dp & 3;
#pragma unroll
    for (int mt = 0; mt < 4; ++mt)
#pragma unroll
      for (int r = 0; r < 4; ++r) {
        int m = m0 + wm * 64 + mt * 16 + quad * 4 + r;
        int win = m >> 6, t = m & 63;
        int i = t >> 3, j = t & 7;
        int b = win >> 6, h1 = (win >> 3) & 7, w1 = win & 7;
        int h = h1 * 32 + i * 4 + p1, w = w1 * 32 + j * 4 + p2;
        out[((b * 64 + c) * 256 + h) * 256 + w] = acc[mt][nt][r] + bv;
      }
  }
}

extern "C" void kernel_launch(void* const* d_in, const int* in_sizes, int n_in,
                              void* d_out, int out_size, void* d_ws, size_t ws_size,
                              hipStream_t stream) {
  const float* x    = (const float*)d_in[0];
  const float* wqkv = (const float*)d_in[1];
  const float* wout = (const float*)d_in[2];
  const float* bout = (const float*)d_in[3];
  float* out = (float*)d_out;
  char* ws = (char*)d_ws;
  if (ws_size < WS_NEED) return;  // insufficient workspace; nothing safe to do

  __hip_bfloat16* tokA  = (__hip_bfloat16*)(ws + OFF_TOKA);
  __hip_bfloat16* oattn = (__hip_bfloat16*)(ws + OFF_TOKA);  // aliases tokA (dead after GEMM1)
  __hip_bfloat16* qkv   = (__hip_bfloat16*)(ws + OFF_QKV);
  __hip_bfloat16* wqT   = (__hip_bfloat16*)(ws + OFF_WQT);
  __hip_bfloat16* woT   = (__hip_bfloat16*)(ws + OFF_WOT);
  float* boP = (float*)(ws + OFF_BO);

  k_perm_wqkv<<<96, 256, 0, stream>>>(wqkv, wqT);
  k_perm_wout<<<32, 256, 0, stream>>>(wout, woT);
  k_perm_bias<<<4, 256, 0, stream>>>(bout, boP);
  k_patchify<<<4096, 256, 0, stream>>>(x, tokA);
  k_gemm_qkv<<<dim3(256, 12), 256, 0, stream>>>(tokA, wqT, qkv);
  k_attn<<<dim3(512, 8), 256, 0, stream>>>(qkv, oattn);
  k_gemm_out<<<dim3(256, 8), 256, 0, stream>>>(oattn, woT, boP, out);
}

// Round 3
// 489.810 us; speedup vs baseline: 1.0839x; 1.0839x over previous
//
#include <hip/hip_runtime.h>
#include <hip/hip_bf16.h>
#include <stdint.h>

typedef __attribute__((ext_vector_type(8))) short short8;
typedef __attribute__((ext_vector_type(4))) float floatx4;

// ---- problem constants ----
constexpr int TD    = 1024;   // token dim
constexpr int E3    = 1536;   // 3*inner
constexpr int INNER = 512;
constexpr int NW    = 512;    // windows
constexpr int M_    = NW * 64; // 32768 tokens

// K-order permutation: reference d = p1*256 + p2*64 + c  <->  d' = c*16 + p1*4 + p2

// ---- workspace layout (bytes) ----
constexpr size_t OFF_TOKA = 0;                                 // tokens bf16 [M, 1024]; oattn aliases later
constexpr size_t OFF_QKV  = (size_t)M_ * TD * 2;               // qkv bf16 [M, 1536]
constexpr size_t OFF_WQT  = OFF_QKV + (size_t)M_ * E3 * 2;     // w_qkv^T bf16 [1536, 1024]
constexpr size_t OFF_WOT  = OFF_WQT + (size_t)E3 * TD * 2;     // w_out^T bf16 [1024, 512]
constexpr size_t OFF_BO   = OFF_WOT + (size_t)TD * INNER * 2;  // bias' fp32 [1024]
constexpr size_t WS_NEED  = OFF_BO + TD * 4;

__device__ __forceinline__ void gl_lds16(const void* g, void* l) {
  __builtin_amdgcn_global_load_lds(
      (const __attribute__((address_space(1))) void*)g,
      (__attribute__((address_space(3))) void*)l, 16, 0, 0);
}

// ---- patchify: x [8,64,256,256] -> tokens bf16 [M, 1024] in d' order ----
__global__ __launch_bounds__(256) void k_patchify(const float* __restrict__ x,
                                                  __hip_bfloat16* __restrict__ tokA) {
  __shared__ __hip_bfloat16 tok[8][1032];
  const int bid = blockIdx.x;
  const int n = bid >> 3, i = bid & 7;
  const int b = n >> 6, h1 = (n >> 3) & 7, w1 = n & 7;
  const int tid = threadIdx.x;
  for (int it = 0; it < 8; ++it) {
    int idx = it * 256 + tid;
    int w4 = idx & 7, p1 = (idx >> 3) & 3, c = idx >> 5;
    int h = h1 * 32 + i * 4 + p1;
    const float4 v = *(const float4*)&x[(((b * 64 + c) * 256 + h) * 256 + w1 * 32 + w4 * 4)];
    __hip_bfloat16* dst = &tok[w4][c * 16 + p1 * 4];
    dst[0] = __float2bfloat16(v.x);
    dst[1] = __float2bfloat16(v.y);
    dst[2] = __float2bfloat16(v.z);
    dst[3] = __float2bfloat16(v.w);
  }
  __syncthreads();
  for (int it = 0; it < 4; ++it) {
    int idx = it * 256 + tid;
    int ch = idx & 127, j = idx >> 7;
    uint4 v = *(const uint4*)&tok[j][ch * 8];
    *(uint4*)&tokA[(size_t)(n * 64 + i * 8 + j) * 1024 + ch * 8] = v;
  }
}

// ---- w_qkv [1024 d][1536 e] fp32 -> wqT bf16 [1536 e][1024 d'] ----
__global__ __launch_bounds__(256) void k_perm_wqkv(const float* __restrict__ wqkv,
                                                   __hip_bfloat16* __restrict__ wqT) {
  __shared__ __hip_bfloat16 wt[16][1032];
  const int e0 = blockIdx.x * 16, tid = threadIdx.x;
  for (int it = 0; it < 64; ++it) {
    int idx = it * 256 + tid;
    int e = idx & 15, d = idx >> 4;
    float v = wqkv[d * 1536 + e0 + e];
    int p1 = d >> 8, p2 = (d >> 6) & 3, c = d & 63;
    wt[e][c * 16 + p1 * 4 + p2] = __float2bfloat16(v);
  }
  __syncthreads();
  for (int it = 0; it < 8; ++it) {
    int idx = it * 256 + tid;
    int ch = idx & 127, e = idx >> 7;
    uint4 v = *(const uint4*)&wt[e][ch * 8];
    *(uint4*)&wqT[(size_t)(e0 + e) * 1024 + ch * 8] = v;
  }
}

// ---- w_out [512 e][1024 d] fp32 -> woT bf16 [1024 d'][512 e] ----
__global__ __launch_bounds__(256) void k_perm_wout(const float* __restrict__ wout,
                                                   __hip_bfloat16* __restrict__ woT) {
  __shared__ __hip_bfloat16 wt[16][1032];
  const int e0 = blockIdx.x * 16, tid = threadIdx.x;
  for (int it = 0; it < 64; ++it) {
    int idx = it * 256 + tid;
    int d = idx & 1023, e = idx >> 10;
    float v = wout[(e0 + e) * 1024 + d];
    int p1 = d >> 8, p2 = (d >> 6) & 3, c = d & 63;
    wt[e][c * 16 + p1 * 4 + p2] = __float2bfloat16(v);
  }
  __syncthreads();
  for (int it = 0; it < 64; ++it) {
    int idx = it * 256 + tid;
    int e = idx & 15, dp = idx >> 4;
    woT[(size_t)dp * 512 + e0 + e] = wt[e][dp];
  }
}

__global__ __launch_bounds__(256) void k_perm_bias(const float* __restrict__ bout,
                                                   float* __restrict__ boP) {
  int dp = blockIdx.x * 256 + threadIdx.x;
  int c = dp >> 4, p1 = (dp >> 2) & 3, p2 = dp & 3;
  boP[dp] = bout[p1 * 256 + p2 * 64 + c];
}

// ---- GEMM1: tokens [M,1024] x wqT^T -> qkv bf16 [M,1536]; XOR-swizzled LDS ----
// grid: (N/128, M/128)  -- n-major so consecutive blocks share the A-tile in L2/L3
__global__ __launch_bounds__(256) void k_gemm_qkv(const __hip_bfloat16* __restrict__ A,
                                                  const __hip_bfloat16* __restrict__ Bt,
                                                  __hip_bfloat16* __restrict__ Cmat) {
  constexpr int K = 1024, N = 1536;
  __shared__ __hip_bfloat16 As[128 * 64];
  __shared__ __hip_bfloat16 Bs[128 * 64];
  const int tid = threadIdx.x;
  const int n0 = blockIdx.x * 128, m0 = blockIdx.y * 128;
  const int lane = tid & 63, wid = tid >> 6;
  const int wm = wid & 1, wn = wid >> 1;
  const int l15 = lane & 15, quad = lane >> 4;
  const int sx = l15 & 7;            // swizzle key (row & 7)
  floatx4 acc[4][4] = {};
  for (int k0 = 0; k0 < K; k0 += 64) {
    __syncthreads();
    for (int it = 0; it < 4; ++it) {
      int ci = it * 256 + tid;
      int r = ci >> 3, chs = ci & 7;
      int ch = chs ^ (r & 7);          // LDS slot chs holds global chunk ch
      gl_lds16(&A[(size_t)(m0 + r) * K + k0 + ch * 8], (char*)As + ci * 16);
      gl_lds16(&Bt[(size_t)(n0 + r) * K + k0 + ch * 8], (char*)Bs + ci * 16);
    }
    __syncthreads();
#pragma unroll
    for (int kk = 0; kk < 64; kk += 32) {
      const int pos = (((kk >> 3) + quad) ^ sx) * 8;   // swizzled chunk offset
      short8 af[4], bf[4];
#pragma unroll
      for (int mt = 0; mt < 4; ++mt)
        af[mt] = *(const short8*)&As[(wm * 64 + mt * 16 + l15) * 64 + pos];
#pragma unroll
      for (int nt = 0; nt < 4; ++nt)
        bf[nt] = *(const short8*)&Bs[(wn * 64 + nt * 16 + l15) * 64 + pos];
#pragma unroll
      for (int mt = 0; mt < 4; ++mt)
#pragma unroll
        for (int nt = 0; nt < 4; ++nt)
          acc[mt][nt] = __builtin_amdgcn_mfma_f32_16x16x32_bf16(af[mt], bf[nt], acc[mt][nt], 0, 0, 0);
    }
  }
#pragma unroll
  for (int mt = 0; mt < 4; ++mt)
#pragma unroll
    for (int nt = 0; nt < 4; ++nt) {
      int col = n0 + wn * 64 + nt * 16 + l15;
#pragma unroll
      for (int r = 0; r < 4; ++r) {
        int row = m0 + wm * 64 + mt * 16 + quad * 4 + r;
        Cmat[(size_t)row * N + col] = __float2bfloat16(acc[mt][nt][r]);
      }
    }
}

// ---- attention: one block per (window, head); swizzled Q/K, bank-clean V transpose ----
__global__ __launch_bounds__(256) void k_attn(const __hip_bfloat16* __restrict__ qkv,
                                              __hip_bfloat16* __restrict__ oattn) {
  __shared__ __hip_bfloat16 Qs[64 * 64];   // [t][dh] swizzled chunks
  __shared__ __hip_bfloat16 Ks[64 * 64];   // [t][dh] swizzled chunks
  __shared__ __hip_bfloat16 Vt[64 * 72];   // [dh][t] padded
  __shared__ __hip_bfloat16 Ps[64 * 72];   // [t][t'] padded; first reused as swizzled Vs[64*64]
  const int win = blockIdx.x, head = blockIdx.y;
  const int tid = threadIdx.x, lane = tid & 63, wid = tid >> 6;
  const int l15 = lane & 15, quad = lane >> 4;
  const int sx = l15 & 7;
  const size_t base = (size_t)win * 64 * 1536 + head * 64;
  for (int l = 0; l < 2; ++l) {
    int idx = l * 256 + tid;
    int t = idx >> 3, ch = idx & 7;
    const size_t rowb = base + (size_t)t * 1536 + ch * 8;
    uint4 q = *(const uint4*)&qkv[rowb];
    uint4 k = *(const uint4*)&qkv[rowb + 512];
    uint4 v = *(const uint4*)&qkv[rowb + 1024];
    const int pos = (ch ^ (t & 7)) * 8;
    *(uint4*)&Qs[t * 64 + pos] = q;
    *(uint4*)&Ks[t * 64 + pos] = k;
    *(uint4*)&Ps[t * 64 + pos] = v;       // Vs staging (swizzled), Ps not yet live
  }
  __syncthreads();
  // transpose V: Vs (swizzled [t][dh]) -> Vt [dh][t]
  {
    const int t = tid & 63, w = tid >> 6;
#pragma unroll
    for (int jn = 0; jn < 2; ++jn) {
      int j = w * 2 + jn;                                  // dh chunk
      short8 v = *(const short8*)&Ps[t * 64 + ((j ^ (t & 7)) * 8)];
#pragma unroll
      for (int jj = 0; jj < 8; ++jj) Vt[(j * 8 + jj) * 72 + t] = ((__hip_bfloat16*)&v)[jj];
    }
  }
  __syncthreads();   // Vs reads done; Ps may now be overwritten by softmax
  // S = Q K^T * scale
  floatx4 sacc[4] = {};
#pragma unroll
  for (int kk = 0; kk < 64; kk += 32) {
    const int pos = (((kk >> 3) + quad) ^ sx) * 8;
    short8 aq = *(const short8*)&Qs[(wid * 16 + l15) * 64 + pos];
#pragma unroll
    for (int ct = 0; ct < 4; ++ct) {
      short8 bk = *(const short8*)&Ks[(ct * 16 + l15) * 64 + pos];
      sacc[ct] = __builtin_amdgcn_mfma_f32_16x16x32_bf16(aq, bk, sacc[ct], 0, 0, 0);
    }
  }
#pragma unroll
  for (int ct = 0; ct < 4; ++ct)
#pragma unroll
    for (int r = 0; r < 4; ++r) sacc[ct][r] = sacc[ct][r] * 0.125f;
  // softmax per row
#pragma unroll
  for (int r = 0; r < 4; ++r) {
    float m = fmaxf(fmaxf(sacc[0][r], sacc[1][r]), fmaxf(sacc[2][r], sacc[3][r]));
    m = fmaxf(m, __shfl_xor(m, 1));
    m = fmaxf(m, __shfl_xor(m, 2));
    m = fmaxf(m, __shfl_xor(m, 4));
    m = fmaxf(m, __shfl_xor(m, 8));
    float ev[4]; float s0 = 0.f;
#pragma unroll
    for (int ct = 0; ct < 4; ++ct) { ev[ct] = __expf(sacc[ct][r] - m); s0 += ev[ct]; }
    s0 += __shfl_xor(s0, 1);
    s0 += __shfl_xor(s0, 2);
    s0 += __shfl_xor(s0, 4);
    s0 += __shfl_xor(s0, 8);
    float inv = 1.0f / s0;
    int row = wid * 16 + quad * 4 + r;
#pragma unroll
    for (int ct = 0; ct < 4; ++ct)
      Ps[row * 72 + ct * 16 + l15] = __float2bfloat16(ev[ct] * inv);
  }
  __syncthreads();
  // O = P V
  floatx4 oacc[4] = {};
#pragma unroll
  for (int kk = 0; kk < 64; kk += 32) {
    const int q8 = quad * 8;
    short8 ap = *(const short8*)&Ps[(wid * 16 + l15) * 72 + kk + q8];
#pragma unroll
    for (int nt = 0; nt < 4; ++nt) {
      short8 bv = *(const short8*)&Vt[(nt * 16 + l15) * 72 + kk + q8];
      oacc[nt] = __builtin_amdgcn_mfma_f32_16x16x32_bf16(ap, bv, oacc[nt], 0, 0, 0);
    }
  }
#pragma unroll
  for (int nt = 0; nt < 4; ++nt) {
    int dh = nt * 16 + l15;
#pragma unroll
    for (int r = 0; r < 4; ++r) {
      int t = wid * 16 + quad * 4 + r;
      oattn[((size_t)win * 64 + t) * 512 + head * 64 + dh] = __float2bfloat16(oacc[nt][r]);
    }
  }
}

// ---- GEMM2 + bias + un-patchify scatter; XOR-swizzled LDS ----
// grid: (N/128, M/128) n-major
__global__ __launch_bounds__(256) void k_gemm_out(const __hip_bfloat16* __restrict__ A,
                                                  const __hip_bfloat16* __restrict__ Bt,
                                                  const float* __restrict__ bias,
                                                  float* __restrict__ out) {
  constexpr int K = 512;
  __shared__ __hip_bfloat16 As[128 * 64];
  __shared__ __hip_bfloat16 Bs[128 * 64];
  const int tid = threadIdx.x;
  const int n0 = blockIdx.x * 128, m0 = blockIdx.y * 128;
  const int lane = tid & 63, wid = tid >> 6;
  const int wm = wid & 1, wn = wid >> 1;
  const int l15 = lane & 15, quad = lane >> 4;
  const int sx = l15 & 7;
  floatx4 acc[4][4] = {};
  for (int k0 = 0; k0 < K; k0 += 64) {
    __syncthreads();
    for (int it = 0; it < 4; ++it) {
      int ci = it * 256 + tid;
      int r = ci >> 3, chs = ci & 7;
      int ch = chs ^ (r & 7);
      gl_lds16(&A[(size_t)(m0 + r) * K + k0 + ch * 8], (char*)As + ci * 16);
      gl_lds16(&Bt[(size_t)(n0 + r) * K + k0 + ch * 8], (char*)Bs + ci * 16);
    }
    __syncthreads();
#pragma unroll
    for (int kk = 0; kk < 64; kk += 32) {
      const int pos = (((kk >> 3) + quad) ^ sx) * 8;
      short8 af[4], bf[4];
#pragma unroll
      for (int mt = 0; mt < 4; ++mt)
        af[mt] = *(const short8*)&As[(wm * 64 + mt * 16 + l15) * 64 + pos];
#pragma unroll
      for (int nt = 0; nt < 4; ++nt)
        bf[nt] = *(const short8*)&Bs[(wn * 64 + nt * 16 + l15) * 64 + pos];
#pragma unroll
      for (int mt = 0; mt < 4; ++mt)
#pragma unroll
        for (int nt = 0; nt < 4; ++nt)
          acc[mt][nt] = __builtin_amdgcn_mfma_f32_16x16x32_bf16(af[mt], bf[nt], acc[mt][nt], 0, 0, 0);
    }
  }
  // epilogue: bias + scatter to [b, c, h, w]
#pragma unroll
  for (int nt = 0; nt < 4; ++nt) {
    int dp = n0 + wn * 64 + nt * 16 + l15;
    float bv = bias[dp];
    int c = dp >> 4, p1 = (dp >> 2) & 3, p2 = dp & 3;
#pragma unroll
    for (int mt = 0; mt < 4; ++mt)
#pragma unroll
      for (int r = 0; r < 4; ++r) {
        int m = m0 + wm * 64 + mt * 16 + quad * 4 + r;
        int win = m >> 6, t = m & 63;
        int i = t >> 3, j = t & 7;
        int b = win >> 6, h1 = (win >> 3) & 7, w1 = win & 7;
        int h = h1 * 32 + i * 4 + p1, w = w1 * 32 + j * 4 + p2;
        out[((b * 64 + c) * 256 + h) * 256 + w] = acc[mt][nt][r] + bv;
      }
  }
}

extern "C" void kernel_launch(void* const* d_in, const int* in_sizes, int n_in,
                              void* d_out, int out_size, void* d_ws, size_t ws_size,
                              hipStream_t stream) {
  const float* x    = (const float*)d_in[0];
  const float* wqkv = (const float*)d_in[1];
  const float* wout = (const float*)d_in[2];
  const float* bout = (const float*)d_in[3];
  float* out = (float*)d_out;
  char* ws = (char*)d_ws;
  if (ws_size < WS_NEED) return;

  __hip_bfloat16* tokA  = (__hip_bfloat16*)(ws + OFF_TOKA);
  __hip_bfloat16* oattn = (__hip_bfloat16*)(ws + OFF_TOKA);  // aliases tokA (dead after GEMM1)
  __hip_bfloat16* qkv   = (__hip_bfloat16*)(ws + OFF_QKV);
  __hip_bfloat16* wqT   = (__hip_bfloat16*)(ws + OFF_WQT);
  __hip_bfloat16* woT   = (__hip_bfloat16*)(ws + OFF_WOT);
  float* boP = (float*)(ws + OFF_BO);

  k_perm_wqkv<<<96, 256, 0, stream>>>(wqkv, wqT);
  k_perm_wout<<<32, 256, 0, stream>>>(wout, woT);
  k_perm_bias<<<4, 256, 0, stream>>>(bout, boP);
  k_patchify<<<4096, 256, 0, stream>>>(x, tokA);
  k_gemm_qkv<<<dim3(12, 256), 256, 0, stream>>>(tokA, wqT, qkv);
  k_attn<<<dim3(512, 8), 256, 0, stream>>>(qkv, oattn);
  k_gemm_out<<<dim3(8, 256), 256, 0, stream>>>(oattn, woT, boP, out);
}